// Round 3
// baseline (975.278 us; speedup 1.0000x reference)
//
#include <hip/hip_runtime.h>
#include <hip/hip_bf16.h>
#include <math.h>

#define En   8
#define Bn   4096
#define Ln   512
#define K1n  1024   // 2L
#define H1n  1024
#define H2n  512
#define Cn   40
#define NP3  48     // layer-3 padded N
#define NTRK 40     // Bn/128 + En row tiles (both GEMMs use TM=128)

// sync counters (ints) in workspace
#define CNT_ROUTE 0
#define CNT_XB    1
#define CNT_W3T   2
#define CNT_OUTI  3
#define CNT_W1T   4              // 128 counters: (e,n0) target 16
#define CNT_W2T   132            // 64 counters: (e,n0) target 16
#define CNT_H1B   196            // 40 counters: per row-tile target 16
#define CNT_TOT   236

typedef unsigned short u16;
typedef __attribute__((ext_vector_type(8))) short bf16x8;
typedef __attribute__((ext_vector_type(4))) float f32x4;

// f32 -> bf16 (RNE), finite inputs
__device__ __forceinline__ u16 f2b(float f) {
    union { float f; unsigned int u; } v; v.f = f;
    unsigned int r = v.u + 0x7FFF + ((v.u >> 16) & 1);
    return (u16)(r >> 16);
}

// async global->LDS 16B copy; LDS dest must be wave-uniform base + lane*16.
__device__ __forceinline__ void g2l16(const void* g, void* l) {
    __builtin_amdgcn_global_load_lds(
        (const __attribute__((address_space(1))) unsigned int*)(unsigned long long)g,
        (__attribute__((address_space(3))) unsigned int*)(unsigned int)(unsigned long long)l,
        16, 0, 0);
}

__device__ __forceinline__ void rel_add(int* c) {
    __hip_atomic_fetch_add(c, 1, __ATOMIC_RELEASE, __HIP_MEMORY_SCOPE_AGENT);
}
// block-uniform acquire spin: tid0 spins (s_sleep-spaced), then block barrier.
__device__ __forceinline__ void acq_spin(int* c, int tgt, int tid) {
    if (tid == 0) {
        while (__hip_atomic_load(c, __ATOMIC_ACQUIRE, __HIP_MEMORY_SCOPE_AGENT) < tgt)
            __builtin_amdgcn_s_sleep(8);
    }
    __syncthreads();
    asm volatile("" ::: "memory");
}

// 64x64 f32->bf16 transpose tile via LDS
__device__ __forceinline__ void wtrans64(
    const float* __restrict__ Wsrc, u16* __restrict__ Wdst,
    int K, int N, int k0, int n0, int tid, float* sm /* [64][65] */)
{
    #pragma unroll
    for (int s = 0; s < 4; s++) {
        int idx = tid + s * 256;
        int kk = idx >> 4, c4 = (idx & 15) * 4;
        float4 v = *(const float4*)&Wsrc[(size_t)(k0 + kk) * N + n0 + c4];
        float* row = sm + kk * 65 + c4;
        row[0] = v.x; row[1] = v.y; row[2] = v.z; row[3] = v.w;
    }
    __syncthreads();
    #pragma unroll
    for (int s = 0; s < 4; s++) {
        int idx = tid + s * 256;
        int nn = idx >> 4, kc = (idx & 15) * 4;
        ushort4 o = make_ushort4(f2b(sm[(kc + 0) * 65 + nn]), f2b(sm[(kc + 1) * 65 + nn]),
                                 f2b(sm[(kc + 2) * 65 + nn]), f2b(sm[(kc + 3) * 65 + nn]));
        *(ushort4*)&Wdst[(size_t)(n0 + nn) * K + k0 + kc] = o;
    }
}

// ---------------------------------------------------------------------------
// Shared GEMM body: TM=128, TN=64, BK=32, K=1024 for both layers.
// 3-stage LDS ring, counted s_waitcnt vmcnt(3) + raw s_barrier per K-step.
// GATHER (L1): A rows gathered via perm; epilogue ELU->h1b + h1b_cnt release.
// FUSE3 (L2): fused layer-3 k-split epilogue, atomicAdd into outf.
// ---------------------------------------------------------------------------
template <int N, bool GATHER, bool FUSE3>
__device__ __forceinline__ void gemm_body(
    int gx, int tid, u16* SM,
    const u16* __restrict__ A, const u16* __restrict__ Wt,
    const float* __restrict__ bias, const int* __restrict__ meta,
    const int* __restrict__ perm, u16* __restrict__ outb,
    const u16* __restrict__ Wt3, float* __restrict__ outf, int* cnts)
{
    constexpr int K = 1024, TM = 128, TN = 64, BK = 32, T = K / BK;
    constexpr int ASLOT = TM * 4, BSLOT = TN * 4, STAGE = ASLOT + BSLOT;
    constexpr int ALOAD = ASLOT / 256, BLOAD = BSLOT / 256;   // 2, 1
    constexpr int HSTR = TN + 8;

    acq_spin(&cnts[CNT_ROUTE], 1, tid);

    const int rt = gx % NTRK;
    const int col0 = (gx / NTRK) * TN;

    int expert = -1, row0 = 0, rowmax = 0, acc_t = 0;
    int prev = meta[0];
    #pragma unroll
    for (int e = 0; e < En; e++) {
        int nxt = meta[e + 1];
        int c = nxt - prev;
        int t = (c + TM - 1) / TM;
        if (expert < 0 && rt < acc_t + t) {
            expert = e; row0 = prev + (rt - acc_t) * TM; rowmax = nxt - 1;
        }
        acc_t += t; prev = nxt;
    }
    if (expert < 0) return;

    // wait for this tile's inputs
    if (GATHER) {
        acq_spin(&cnts[CNT_XB], 256, tid);
        acq_spin(&cnts[CNT_W1T + expert * 16 + (col0 >> 6)], 16, tid);
    } else {
        acq_spin(&cnts[CNT_W2T + expert * 8 + (col0 >> 6)], 16, tid);
        acq_spin(&cnts[CNT_H1B + rt], 16, tid);
    }

    const u16* Wexp = Wt + (size_t)expert * N * K;

    const int lane = tid & 63;
    const int wid = tid >> 6;
    const int wm = (wid & 1) * (TM / 2);
    const int wn = (wid >> 1) * (TN / 2);
    const int l15 = lane & 15;
    const int lq = lane >> 4;

    // staging: slot idx -> row rl = idx>>2, slot c = idx&3 holds global
    // k-chunk c^((rl>>1)&3); LDS off = 16B * (stagebase + region + idx).
    const u16* aptr[ALOAD]; int aoff[ALOAD];
    const u16* bptr[BLOAD]; int boff[BLOAD];
    #pragma unroll
    for (int s = 0; s < ALOAD; s++) {
        int idx = tid + s * 256;
        int rl = idx >> 2, c = idx & 3;
        int kq = c ^ ((rl >> 1) & 3);
        int rg = row0 + rl; if (rg > rowmax) rg = rowmax;
        if (GATHER) rg = perm[rg];
        aptr[s] = A + (size_t)rg * K + kq * 8;
        aoff[s] = idx * 8;
    }
    #pragma unroll
    for (int s = 0; s < BLOAD; s++) {
        int idx = tid + s * 256;
        int rl = idx >> 2, c = idx & 3;
        int kq = c ^ ((rl >> 1) & 3);
        bptr[s] = Wexp + (size_t)(col0 + rl) * K + kq * 8;
        boff[s] = ASLOT * 8 + idx * 8;
    }

    constexpr int MI = TM / 32, NJ = TN / 32;
    f32x4 acc[MI][NJ];
    #pragma unroll
    for (int i = 0; i < MI; i++)
        #pragma unroll
        for (int j = 0; j < NJ; j++) acc[i][j] = (f32x4){0.f, 0.f, 0.f, 0.f};

    const int cp = (lq ^ ((l15 >> 1) & 3)) * 8;

    auto stage_issue = [&](int buf, int t) {
        const int base = buf * (STAGE * 8);
        const int ko = t * BK;
        #pragma unroll
        for (int s = 0; s < ALOAD; s++) g2l16(aptr[s] + ko, &SM[base + aoff[s]]);
        #pragma unroll
        for (int s = 0; s < BLOAD; s++) g2l16(bptr[s] + ko, &SM[base + boff[s]]);
    };
    auto kstep = [&](int buf) {
        const u16* As = &SM[buf * (STAGE * 8)];
        const u16* Bs = As + ASLOT * 8;
        bf16x8 af[MI], bf[NJ];
        #pragma unroll
        for (int i = 0; i < MI; i++)
            af[i] = *(const bf16x8*)&As[(wm + i * 16 + l15) * BK + cp];
        #pragma unroll
        for (int j = 0; j < NJ; j++)
            bf[j] = *(const bf16x8*)&Bs[(wn + j * 16 + l15) * BK + cp];
        #pragma unroll
        for (int i = 0; i < MI; i++)
            #pragma unroll
            for (int j = 0; j < NJ; j++)
                acc[i][j] = __builtin_amdgcn_mfma_f32_16x16x32_bf16(
                    af[i], bf[j], acc[i][j], 0, 0, 0);
    };

    stage_issue(0, 0);
    asm volatile("" ::: "memory");
    stage_issue(1, 1);
    asm volatile("" ::: "memory");

    int rb = 0;
    for (int t = 0; t < T - 1; t++) {
        asm volatile("s_waitcnt vmcnt(3) lgkmcnt(0)" ::: "memory");
        __builtin_amdgcn_s_barrier();
        asm volatile("" ::: "memory");
        if (t + 2 < T) {
            int wb = rb + 2; if (wb >= 3) wb -= 3;
            stage_issue(wb, t + 2);
        }
        asm volatile("" ::: "memory");
        kstep(rb);
        rb = (rb == 2) ? 0 : rb + 1;
    }
    asm volatile("s_waitcnt vmcnt(0) lgkmcnt(0)" ::: "memory");
    __builtin_amdgcn_s_barrier();
    asm volatile("" ::: "memory");
    kstep(rb);

    if (!FUSE3) {
        // bias + ELU -> h1b bf16.  C/D: col=l15, row=lq*4+reg
        #pragma unroll
        for (int i = 0; i < MI; i++) {
            #pragma unroll
            for (int j = 0; j < NJ; j++) {
                int col = col0 + wn + j * 16 + l15;
                float bv = bias[expert * N + col];
                #pragma unroll
                for (int r = 0; r < 4; r++) {
                    int grow = row0 + wm + i * 16 + lq * 4 + r;
                    if (grow <= rowmax) {
                        float v = acc[i][j][r] + bv;
                        v = (v > 0.f) ? v : (expf(v) - 1.f);
                        outb[(size_t)grow * N + col] = f2b(v);
                    }
                }
            }
        }
        __threadfence();
        __syncthreads();
        if (tid == 0) rel_add(&cnts[CNT_H1B + rt]);
    } else {
        // fused layer 3: k-split over this block's TN h-cols
        __syncthreads();
        u16* H = &SM[0];   // [TM][HSTR] bf16
        #pragma unroll
        for (int i = 0; i < MI; i++) {
            #pragma unroll
            for (int j = 0; j < NJ; j++) {
                int col = wn + j * 16 + l15;
                float bv = bias[expert * N + col0 + col];
                #pragma unroll
                for (int r = 0; r < 4; r++) {
                    float v = acc[i][j][r] + bv;
                    v = (v > 0.f) ? v : (expf(v) - 1.f);
                    H[(wm + i * 16 + lq * 4 + r) * HSTR + col] = f2b(v);
                }
            }
        }
        __syncthreads();
        acq_spin(&cnts[CNT_W3T], 128, tid);
        acq_spin(&cnts[CNT_OUTI], 64, tid);
        constexpr int RI = TM / 64;
        constexpr int KC = TN / 32;
        const int rh = wid * (TM / 4);
        f32x4 a3[RI][3];
        #pragma unroll
        for (int ri = 0; ri < RI; ri++)
            #pragma unroll
            for (int j = 0; j < 3; j++) a3[ri][j] = (f32x4){0.f, 0.f, 0.f, 0.f};
        #pragma unroll
        for (int ki = 0; ki < KC; ki++) {
            bf16x8 ha[RI];
            #pragma unroll
            for (int ri = 0; ri < RI; ri++)
                ha[ri] = *(const bf16x8*)&H[(rh + ri * 16 + l15) * HSTR + ki * 32 + lq * 8];
            #pragma unroll
            for (int j = 0; j < 3; j++) {
                bf16x8 wb = *(const bf16x8*)
                    &Wt3[((size_t)expert * NP3 + j * 16 + l15) * H2n + col0 + ki * 32 + lq * 8];
                #pragma unroll
                for (int ri = 0; ri < RI; ri++)
                    a3[ri][j] = __builtin_amdgcn_mfma_f32_16x16x32_bf16(
                        ha[ri], wb, a3[ri][j], 0, 0, 0);
            }
        }
        #pragma unroll
        for (int j = 0; j < 3; j++) {
            int col = j * 16 + l15;
            if (col < Cn) {
                #pragma unroll
                for (int ri = 0; ri < RI; ri++) {
                    #pragma unroll
                    for (int r = 0; r < 4; r++) {
                        int grow = row0 + rh + ri * 16 + lq * 4 + r;
                        if (grow <= rowmax)
                            atomicAdd(&outf[(size_t)perm[grow] * Cn + col], a3[ri][j][r]);
                    }
                }
            }
        }
    }
}

// ---------------------------------------------------------------------------
// ONE kernel, 1025 blocks.
//   [0,640)    L1 GEMM; prework: 2048 W1t transpose tiles + 256 Xb jobs
//   [640,705)  route (1) + out-init (64)   — non-spinning
//   [705,1025) L2 GEMM; prework: 1024 W2t tiles + 128 W3t jobs
// Deadlock-free: LDS 36 KB -> 4 blocks/CU guaranteed (launch_bounds(256,4)
// caps VGPR<=128) -> 1024 resident slots >= 960 spinners; every awaited
// producer is a co-resident-capable spinner or a retiring non-spinner.
// ---------------------------------------------------------------------------
__global__ __launch_bounds__(256, 4) void fused_moe(
    const float* __restrict__ xs, const float* __restrict__ xp,
    const float* __restrict__ W1, const float* __restrict__ b1,
    const float* __restrict__ W2, const float* __restrict__ b2,
    const float* __restrict__ W3, const float* __restrict__ b3,
    const int* __restrict__ label, float* __restrict__ out,
    int* __restrict__ meta, int* __restrict__ perm,
    u16* __restrict__ Xb, u16* __restrict__ W1t, u16* __restrict__ W2t,
    u16* __restrict__ h1b, u16* __restrict__ W3t, int* __restrict__ cnts)
{
    __shared__ __align__(16) u16 SM[18432];   // 36 KB: 3-ring staging / scratch
    const int bx = blockIdx.x;
    const int tid = threadIdx.x;

    if (bx < 640) {
        // ---- L1 prework: W1t tiles (0..2047) then Xb jobs (2048..2303) ----
        #pragma unroll
        for (int s = 0; s < 4; s++) {
            int j = bx + 640 * s;
            if (j < 2048) {
                int e = j >> 8, rem = j & 255;
                wtrans64(W1 + (size_t)e * K1n * H1n, W1t + (size_t)e * H1n * K1n,
                         K1n, H1n, (rem >> 4) * 64, (rem & 15) * 64, tid, (float*)SM);
                __threadfence();
                __syncthreads();
                if (tid == 0) rel_add(&cnts[CNT_W1T + e * 16 + (rem & 15)]);
            } else if (j < 2304) {
                int r0 = (j - 2048) * 16;
                #pragma unroll 4
                for (int q = 0; q < 16; q++) {
                    int r = r0 + q;
                    int k = tid * 4;
                    const float* src = (k < Ln) ? (xp + (size_t)r * Ln + k)
                                                : (xs + (size_t)r * Ln + (k - Ln));
                    float4 v = *(const float4*)src;
                    *(ushort4*)&Xb[(size_t)r * K1n + k] =
                        make_ushort4(f2b(v.x), f2b(v.y), f2b(v.z), f2b(v.w));
                }
                __threadfence();
                __syncthreads();
                if (tid == 0) rel_add(&cnts[CNT_XB]);
            }
        }
        // XCD swizzle within the 640-block range (640 = 8*80)
        int gx = (bx & 7) * 80 + (bx >> 3);
        gemm_body<H1n, true, false>(gx, tid, SM, Xb, W1t, b1, meta, perm,
                                    h1b, nullptr, nullptr, cnts);
    } else if (bx < 705) {
        int jb = bx - 640;
        if (jb == 0) {
            // ---- route: histogram + prefix + stable permutation ----
            int* cnt = (int*)SM;
            int* off = cnt + En;
            if (tid < En) cnt[tid] = 0;
            __syncthreads();
            for (int b = tid; b < Bn; b += 256) atomicAdd(&cnt[label[b]], 1);
            __syncthreads();
            if (tid == 0) {
                int run = 0;
                for (int e = 0; e < En; e++) { off[e] = run; run += cnt[e]; }
                off[En] = run;
            }
            __syncthreads();
            if (tid < En) cnt[tid] = off[tid];
            __syncthreads();
            for (int b = tid; b < Bn; b += 256) {
                int e = label[b];
                perm[atomicAdd(&cnt[e], 1)] = b;
            }
            if (tid <= En) meta[tid] = off[tid];
            __threadfence();
            __syncthreads();
            if (tid == 0) rel_add(&cnts[CNT_ROUTE]);
        } else {
            // ---- out bias pre-init (64 jobs x 64 rows) ----
            int r0 = (jb - 1) * 64;
            #pragma unroll
            for (int s = 0; s < 10; s++) {
                int idx = tid + s * 256;
                int r = r0 + idx / Cn;
                int c = idx - (idx / Cn) * Cn;
                out[(size_t)r * Cn + c] = b3[label[r] * Cn + c];
            }
            __threadfence();
            __syncthreads();
            if (tid == 0) rel_add(&cnts[CNT_OUTI]);
        }
    } else {
        int lx = bx - 705;
        // ---- L2 prework: W2t tiles (0..1023) then W3t jobs (1024..1151) ----
        #pragma unroll
        for (int s = 0; s < 4; s++) {
            int j = lx + 320 * s;
            if (j < 1024) {
                int e = j >> 7, rem = j & 127;
                wtrans64(W2 + (size_t)e * H1n * H2n, W2t + (size_t)e * H2n * H1n,
                         H1n, H2n, (rem >> 3) * 64, (rem & 7) * 64, tid, (float*)SM);
                __threadfence();
                __syncthreads();
                if (tid == 0) rel_add(&cnts[CNT_W2T + e * 8 + (rem & 7)]);
            } else if (j < 1152) {
                int b = j - 1024;
                int e = b >> 4, k0 = (b & 15) * 32;
                const float* src = W3 + (size_t)e * H2n * Cn;
                u16* dst = W3t + (size_t)e * NP3 * H2n;
                float* t = (float*)SM;     // [32][41]
                #pragma unroll
                for (int q = 0; q < 5; q++) {
                    int idx = tid + q * 256;
                    int kk = idx / Cn, nn = idx - kk * Cn;
                    if (kk < 32) t[kk * 41 + nn] = src[(size_t)(k0 + kk) * Cn + nn];
                }
                __syncthreads();
                #pragma unroll
                for (int q = 0; q < 6; q++) {
                    int idx = tid + q * 256;
                    int nn = idx >> 5, kk = idx & 31;
                    float v = (nn < Cn) ? t[kk * 41 + nn] : 0.f;
                    dst[(size_t)nn * H2n + k0 + kk] = f2b(v);
                }
                __threadfence();
                __syncthreads();
                if (tid == 0) rel_add(&cnts[CNT_W3T]);
            }
        }
        // XCD swizzle within the 320-block range (320 = 8*40)
        int gx = (lx & 7) * 40 + (lx >> 3);
        gemm_body<H2n, false, true>(gx, tid, SM, h1b, W2t, b2, meta, perm,
                                    nullptr, W3t, out, cnts);
    }
}

// ---------------------------------------------------------------------------
extern "C" void kernel_launch(void* const* d_in, const int* in_sizes, int n_in,
                              void* d_out, int out_size, void* d_ws, size_t ws_size,
                              hipStream_t stream)
{
    const float* xs = (const float*)d_in[0];
    const float* xp = (const float*)d_in[1];
    const float* W1 = (const float*)d_in[2];
    const float* b1 = (const float*)d_in[3];
    const float* W2 = (const float*)d_in[4];
    const float* b2 = (const float*)d_in[5];
    const float* W3 = (const float*)d_in[6];
    const float* b3 = (const float*)d_in[7];
    const int* label = (const int*)d_in[8];
    float* out = (float*)d_out;

    char* ws = (char*)d_ws;
    int* meta = (int*)ws;                                    // 64 B
    int* perm = (int*)(ws + 64);                             // 16 KB
    int* cnts = (int*)(ws + 20480);                          // 944 B
    u16* Xb  = (u16*)(ws + (64 << 10));                      // 8 MB [4096][1024]
    u16* W1t = (u16*)(ws + (64 << 10) + (8  << 20));         // 16 MB [8][1024][1024]
    u16* W2t = (u16*)(ws + (64 << 10) + (24 << 20));         // 8 MB  [8][512][1024]
    u16* h1b = (u16*)(ws + (64 << 10) + (32 << 20));         // 8 MB  [4096][1024] (sorted)
    u16* W3t = (u16*)(ws + (64 << 10) + (40 << 20));         // 393 KB [8][48][512]

    hipMemsetAsync(cnts, 0, CNT_TOT * sizeof(int), stream);

    fused_moe<<<1025, 256, 0, stream>>>(
        xs, xp, W1, b1, W2, b2, W3, b3, label, out,
        meta, perm, Xb, W1t, W2t, h1b, W3t, cnts);
}

// Round 5
// 169.898 us; speedup vs baseline: 5.7404x; 5.7404x over previous
//
#include <hip/hip_runtime.h>
#include <hip/hip_bf16.h>
#include <math.h>

#define En   8
#define Bn   4096
#define Ln   512
#define K1n  1024   // 2L
#define H1n  1024
#define H2n  512
#define Cn   40
#define NP3  48     // layer-3 padded N

typedef unsigned short u16;
typedef __attribute__((ext_vector_type(8))) short bf16x8;
typedef __attribute__((ext_vector_type(4))) float f32x4;

// f32 -> bf16 (RNE), finite inputs
__device__ __forceinline__ u16 f2b(float f) {
    union { float f; unsigned int u; } v; v.f = f;
    unsigned int r = v.u + 0x7FFF + ((v.u >> 16) & 1);
    return (u16)(r >> 16);
}

// async global->LDS 16B copy; LDS dest must be wave-uniform base + lane*16.
__device__ __forceinline__ void g2l16(const void* g, void* l) {
    __builtin_amdgcn_global_load_lds(
        (const __attribute__((address_space(1))) unsigned int*)(unsigned long long)g,
        (__attribute__((address_space(3))) unsigned int*)(unsigned int)(unsigned long long)l,
        16, 0, 0);
}

// 64x64 f32->bf16 transpose tile via LDS
__device__ __forceinline__ void wtrans64(
    const float* __restrict__ Wsrc, u16* __restrict__ Wdst,
    int K, int N, int k0, int n0, int tid, float* sm /* [64][65] */)
{
    #pragma unroll
    for (int s = 0; s < 4; s++) {
        int idx = tid + s * 256;
        int kk = idx >> 4, c4 = (idx & 15) * 4;
        float4 v = *(const float4*)&Wsrc[(size_t)(k0 + kk) * N + n0 + c4];
        float* row = sm + kk * 65 + c4;
        row[0] = v.x; row[1] = v.y; row[2] = v.z; row[3] = v.w;
    }
    __syncthreads();
    #pragma unroll
    for (int s = 0; s < 4; s++) {
        int idx = tid + s * 256;
        int nn = idx >> 4, kc = (idx & 15) * 4;
        ushort4 o = make_ushort4(f2b(sm[(kc + 0) * 65 + nn]), f2b(sm[(kc + 1) * 65 + nn]),
                                 f2b(sm[(kc + 2) * 65 + nn]), f2b(sm[(kc + 3) * 65 + nn]));
        *(ushort4*)&Wdst[(size_t)(n0 + nn) * K + k0 + kc] = o;
    }
}

// ---------------------------------------------------------------------------
// prep_all: ALL independent prework, one job per block, max parallelism.
//   [0]            route
//   [1, 257)       Xb  f32->bf16 concat      (256 jobs x 16 rows)
//   [257, 2305)    W1t transpose             (2048 tiles)
//   [2305, 3329)   W2t transpose             (1024 tiles)
//   [3329, 3457)   W3t transpose+pad         (128 jobs)
//   [3457, 3521)   out bias pre-init         (64 jobs x 64 rows)
// ---------------------------------------------------------------------------
#define PA_TOT 3521

__global__ __launch_bounds__(256) void prep_all(
    const float* __restrict__ xs, const float* __restrict__ xp,
    const float* __restrict__ W1, const float* __restrict__ W2,
    const float* __restrict__ W3, const float* __restrict__ b3,
    const int* __restrict__ label,
    int* __restrict__ meta, int* __restrict__ perm,
    u16* __restrict__ Xb, u16* __restrict__ W1t, u16* __restrict__ W2t,
    u16* __restrict__ W3t, float* __restrict__ outf)
{
    __shared__ __align__(16) float sm[64 * 65];
    const int bid = blockIdx.x;
    const int tid = threadIdx.x;

    if (bid == 0) {
        // route: histogram + prefix + stable permutation
        int* cnt = (int*)sm;
        int* off = cnt + En;
        if (tid < En) cnt[tid] = 0;
        __syncthreads();
        for (int b = tid; b < Bn; b += 256) atomicAdd(&cnt[label[b]], 1);
        __syncthreads();
        if (tid == 0) {
            int run = 0;
            for (int e = 0; e < En; e++) { off[e] = run; run += cnt[e]; }
            off[En] = run;
        }
        __syncthreads();
        if (tid < En) cnt[tid] = off[tid];
        __syncthreads();
        for (int b = tid; b < Bn; b += 256) {
            int e = label[b];
            perm[atomicAdd(&cnt[e], 1)] = b;
        }
        if (tid <= En) meta[tid] = off[tid];
    } else if (bid < 257) {
        int r0 = (bid - 1) * 16;
        #pragma unroll 4
        for (int s = 0; s < 16; s++) {
            int r = r0 + s;
            int k = tid * 4;
            const float* src = (k < Ln) ? (xp + (size_t)r * Ln + k)
                                        : (xs + (size_t)r * Ln + (k - Ln));
            float4 v = *(const float4*)src;
            *(ushort4*)&Xb[(size_t)r * K1n + k] =
                make_ushort4(f2b(v.x), f2b(v.y), f2b(v.z), f2b(v.w));
        }
    } else if (bid < 2305) {
        int b = bid - 257;
        int e = b >> 8, rem = b & 255;
        wtrans64(W1 + (size_t)e * K1n * H1n, W1t + (size_t)e * H1n * K1n,
                 K1n, H1n, (rem >> 4) * 64, (rem & 15) * 64, tid, sm);
    } else if (bid < 3329) {
        int b = bid - 2305;
        int e = b >> 7, rem = b & 127;
        wtrans64(W2 + (size_t)e * H1n * H2n, W2t + (size_t)e * H2n * H1n,
                 H1n, H2n, (rem >> 3) * 64, (rem & 7) * 64, tid, sm);
    } else if (bid < 3457) {
        int b = bid - 3329;
        int e = b >> 4, k0 = (b & 15) * 32;
        const float* src = W3 + (size_t)e * H2n * Cn;
        u16* dst = W3t + (size_t)e * NP3 * H2n;
        float* t = sm;     // [32][41]
        #pragma unroll
        for (int q = 0; q < 5; q++) {
            int idx = tid + q * 256;
            int kk = idx / Cn, nn = idx - kk * Cn;
            if (kk < 32) t[kk * 41 + nn] = src[(size_t)(k0 + kk) * Cn + nn];
        }
        __syncthreads();
        #pragma unroll
        for (int q = 0; q < 6; q++) {
            int idx = tid + q * 256;
            int nn = idx >> 5, kk = idx & 31;
            float v = (nn < Cn) ? t[kk * 41 + nn] : 0.f;
            dst[(size_t)nn * H2n + k0 + kk] = f2b(v);
        }
    } else {
        int r0 = (bid - 3457) * 64;
        #pragma unroll
        for (int s = 0; s < 10; s++) {
            int idx = tid + s * 256;
            int r = r0 + idx / Cn;
            int c = idx - (idx / Cn) * Cn;
            outf[(size_t)r * Cn + c] = b3[label[r] * Cn + c];
        }
    }
}

// ---------------------------------------------------------------------------
// Grouped bf16 MFMA GEMM.
//   TM x TN tile, BK=32, 4 waves each a (TM/2)x(TN/2) quadrant.
//   4-stage LDS ring, counted s_waitcnt per K-step (never vmcnt(0) until the
//   2-step tail peel): steady-state wait vmcnt(2*LW) -> stage t resident
//   while stages t+1,t+2 stay in flight (~3 iters = ~960cy of load slack).
//   Barrier sandwich: [asm waitcnt(mem)][s_barrier][asm ""(mem)].
// LDS chunk swizzle (BK=32, 4 x 16B chunks/row): chunk c of row r stored at
//   slot c ^ ((r>>1)&3)  -> ds_read_b128 lands 2 lanes/bank-quad (free).
// XCD-aware bijective swizzle on the block range (NGEMM % 8 == 0).
// FUSE3 (L2 instance): fused layer-3 k-split epilogue, atomicAdd into outf.
// ---------------------------------------------------------------------------
template <int K, int N, int TM, int TN, bool GATHER, bool FUSE3>
__global__ __launch_bounds__(256) void mfma_gemm(
    const u16* __restrict__ A, const u16* __restrict__ Wt,
    const float* __restrict__ bias, const int* __restrict__ meta,
    const int* __restrict__ perm, u16* __restrict__ outb,
    const u16* __restrict__ Wt3, float* __restrict__ outf)
{
    constexpr int BK    = 32;
    constexpr int T     = K / BK;
    constexpr int NTC   = N / TN;
    constexpr int NTRk  = Bn / TM + En;      // max row tiles
    constexpr int NGEMM = NTRk * NTC;
    constexpr int ASLOT = TM * 4;            // 16B chunks per A stage
    constexpr int BSLOT = TN * 4;
    constexpr int STAGE = ASLOT + BSLOT;     // chunks per stage
    constexpr int ALOAD = ASLOT / 256;       // g2l16 per thread (A)
    constexpr int BLOAD = BSLOT / 256;       // g2l16 per thread (B)
    constexpr int LW    = ALOAD + BLOAD;     // loads/thread/stage
    constexpr int HSTR  = TN + 8;            // fused-L3 H tile stride (u16)
    constexpr int SMST  = 4 * STAGE * 8;     // staging u16 count (4 stages)
    constexpr int SMU16 = (FUSE3 && (TM * HSTR) > SMST) ? (TM * HSTR) : SMST;
    __shared__ __align__(16) u16 SM[SMU16];

    const int tid = threadIdx.x;
    const int bx = blockIdx.x;

    // XCD-aware bijective block swizzle (NGEMM % 8 == 0)
    const int gx = (bx & 7) * (NGEMM / 8) + (bx >> 3);
    const int rt = gx % NTRk;
    const int col0 = (gx / NTRk) * TN;

    int expert = -1, row0 = 0, rowmax = 0, acc_t = 0;
    int prev = meta[0];
    #pragma unroll
    for (int e = 0; e < En; e++) {
        int nxt = meta[e + 1];
        int c = nxt - prev;
        int t = (c + TM - 1) / TM;
        if (expert < 0 && rt < acc_t + t) {
            expert = e; row0 = prev + (rt - acc_t) * TM; rowmax = nxt - 1;
        }
        acc_t += t; prev = nxt;
    }
    if (expert < 0) return;

    const u16* Wexp = Wt + (size_t)expert * N * K;

    const int lane = tid & 63;
    const int wid = tid >> 6;
    const int wm = (wid & 1) * (TM / 2);
    const int wn = (wid >> 1) * (TN / 2);
    const int l15 = lane & 15;
    const int lq = lane >> 4;

    // staging: slot idx -> row rl = idx>>2, slot c = idx&3 holds global
    // k-chunk c^((rl>>1)&3); LDS off = 16B * (stagebase + region + idx).
    const u16* aptr[ALOAD]; int aoff[ALOAD];
    const u16* bptr[BLOAD]; int boff[BLOAD];
    #pragma unroll
    for (int s = 0; s < ALOAD; s++) {
        int idx = tid + s * 256;
        int rl = idx >> 2, c = idx & 3;
        int kq = c ^ ((rl >> 1) & 3);
        int rg = row0 + rl; if (rg > rowmax) rg = rowmax;
        if (GATHER) rg = perm[rg];
        aptr[s] = A + (size_t)rg * K + kq * 8;
        aoff[s] = idx * 8;
    }
    #pragma unroll
    for (int s = 0; s < BLOAD; s++) {
        int idx = tid + s * 256;
        int rl = idx >> 2, c = idx & 3;
        int kq = c ^ ((rl >> 1) & 3);
        bptr[s] = Wexp + (size_t)(col0 + rl) * K + kq * 8;
        boff[s] = ASLOT * 8 + idx * 8;
    }

    constexpr int MI = TM / 32;    // 16-row fragments per wave (M)
    constexpr int NJ = TN / 32;    // 16-col fragments per wave (N)
    f32x4 acc[MI][NJ];
    #pragma unroll
    for (int i = 0; i < MI; i++)
        #pragma unroll
        for (int j = 0; j < NJ; j++) acc[i][j] = (f32x4){0.f, 0.f, 0.f, 0.f};

    // read-side swizzled chunk offset (u16): row bits 1..2 == l15 bits 1..2
    const int cp = (lq ^ ((l15 >> 1) & 3)) * 8;

    auto stage_issue = [&](int buf, int t) {
        const int base = buf * (STAGE * 8);
        const int ko = t * BK;
        #pragma unroll
        for (int s = 0; s < ALOAD; s++) g2l16(aptr[s] + ko, &SM[base + aoff[s]]);
        #pragma unroll
        for (int s = 0; s < BLOAD; s++) g2l16(bptr[s] + ko, &SM[base + boff[s]]);
    };
    auto kstep = [&](int buf) {
        const u16* As = &SM[buf * (STAGE * 8)];
        const u16* Bs = As + ASLOT * 8;
        bf16x8 af[MI], bf[NJ];
        #pragma unroll
        for (int i = 0; i < MI; i++)
            af[i] = *(const bf16x8*)&As[(wm + i * 16 + l15) * BK + cp];
        #pragma unroll
        for (int j = 0; j < NJ; j++)
            bf[j] = *(const bf16x8*)&Bs[(wn + j * 16 + l15) * BK + cp];
        #pragma unroll
        for (int i = 0; i < MI; i++)
            #pragma unroll
            for (int j = 0; j < NJ; j++)
                acc[i][j] = __builtin_amdgcn_mfma_f32_16x16x32_bf16(
                    af[i], bf[j], acc[i][j], 0, 0, 0);
    };

    // prologue: stages 0,1,2 (ordered issue groups for exact vmcnt counting)
    stage_issue(0, 0);
    asm volatile("" ::: "memory");
    stage_issue(1, 1);
    asm volatile("" ::: "memory");
    stage_issue(2, 2);
    asm volatile("" ::: "memory");

    int rb = 0;   // buffer read this iteration
    for (int t = 0; t < T - 2; t++) {
        // steady state: stages t+1,t+2 may stay in flight (2*LW loads)
        if constexpr (LW == 2)
            asm volatile("s_waitcnt vmcnt(4) lgkmcnt(0)" ::: "memory");
        else
            asm volatile("s_waitcnt vmcnt(6) lgkmcnt(0)" ::: "memory");
        __builtin_amdgcn_s_barrier();
        asm volatile("" ::: "memory");
        if (t + 3 < T) stage_issue((rb + 3) & 3, t + 3);
        asm volatile("" ::: "memory");
        kstep(rb);
        rb = (rb + 1) & 3;
    }
    // t = T-2: only stage T-1 may remain in flight (LW loads)
    if constexpr (LW == 2)
        asm volatile("s_waitcnt vmcnt(2) lgkmcnt(0)" ::: "memory");
    else
        asm volatile("s_waitcnt vmcnt(3) lgkmcnt(0)" ::: "memory");
    __builtin_amdgcn_s_barrier();
    asm volatile("" ::: "memory");
    kstep(rb);
    rb = (rb + 1) & 3;
    // t = T-1: full drain
    asm volatile("s_waitcnt vmcnt(0) lgkmcnt(0)" ::: "memory");
    __builtin_amdgcn_s_barrier();
    asm volatile("" ::: "memory");
    kstep(rb);

    if (!FUSE3) {
        // bias + ELU -> global bf16.  C/D: col=l15, row=lq*4+reg
        #pragma unroll
        for (int i = 0; i < MI; i++) {
            #pragma unroll
            for (int j = 0; j < NJ; j++) {
                int col = col0 + wn + j * 16 + l15;
                float bv = bias[expert * N + col];
                #pragma unroll
                for (int r = 0; r < 4; r++) {
                    int grow = row0 + wm + i * 16 + lq * 4 + r;
                    if (grow <= rowmax) {
                        float v = acc[i][j][r] + bv;
                        v = (v > 0.f) ? v : (expf(v) - 1.f);
                        outb[(size_t)grow * N + col] = f2b(v);
                    }
                }
            }
        }
    } else {
        // fused layer 3: k-split over this block's TN h-cols
        __syncthreads();
        u16* H = &SM[0];   // [TM][HSTR] bf16
        #pragma unroll
        for (int i = 0; i < MI; i++) {
            #pragma unroll
            for (int j = 0; j < NJ; j++) {
                int col = wn + j * 16 + l15;
                float bv = bias[expert * N + col0 + col];
                #pragma unroll
                for (int r = 0; r < 4; r++) {
                    float v = acc[i][j][r] + bv;
                    v = (v > 0.f) ? v : (expf(v) - 1.f);
                    H[(wm + i * 16 + lq * 4 + r) * HSTR + col] = f2b(v);
                }
            }
        }
        __syncthreads();
        constexpr int RI = TM / 64;         // 16-row frags per wave (TM/4 rows)
        constexpr int KC = TN / 32;         // k-chunks over this block's h-cols
        const int rh = wid * (TM / 4);
        f32x4 a3[RI][3];
        #pragma unroll
        for (int ri = 0; ri < RI; ri++)
            #pragma unroll
            for (int j = 0; j < 3; j++) a3[ri][j] = (f32x4){0.f, 0.f, 0.f, 0.f};
        #pragma unroll
        for (int ki = 0; ki < KC; ki++) {
            bf16x8 ha[RI];
            #pragma unroll
            for (int ri = 0; ri < RI; ri++)
                ha[ri] = *(const bf16x8*)&H[(rh + ri * 16 + l15) * HSTR + ki * 32 + lq * 8];
            #pragma unroll
            for (int j = 0; j < 3; j++) {
                bf16x8 wb = *(const bf16x8*)
                    &Wt3[((size_t)expert * NP3 + j * 16 + l15) * H2n + col0 + ki * 32 + lq * 8];
                #pragma unroll
                for (int ri = 0; ri < RI; ri++)
                    a3[ri][j] = __builtin_amdgcn_mfma_f32_16x16x32_bf16(
                        ha[ri], wb, a3[ri][j], 0, 0, 0);
            }
        }
        #pragma unroll
        for (int j = 0; j < 3; j++) {
            int col = j * 16 + l15;
            if (col < Cn) {
                #pragma unroll
                for (int ri = 0; ri < RI; ri++) {
                    #pragma unroll
                    for (int r = 0; r < 4; r++) {
                        int grow = row0 + rh + ri * 16 + lq * 4 + r;
                        if (grow <= rowmax)
                            atomicAdd(&outf[(size_t)perm[grow] * Cn + col], a3[ri][j][r]);
                    }
                }
            }
        }
    }
}

// ---------------------------------------------------------------------------
extern "C" void kernel_launch(void* const* d_in, const int* in_sizes, int n_in,
                              void* d_out, int out_size, void* d_ws, size_t ws_size,
                              hipStream_t stream)
{
    const float* xs = (const float*)d_in[0];
    const float* xp = (const float*)d_in[1];
    const float* W1 = (const float*)d_in[2];
    const float* b1 = (const float*)d_in[3];
    const float* W2 = (const float*)d_in[4];
    const float* b2 = (const float*)d_in[5];
    const float* W3 = (const float*)d_in[6];
    const float* b3 = (const float*)d_in[7];
    const int* label = (const int*)d_in[8];
    float* out = (float*)d_out;

    char* ws = (char*)d_ws;
    int* meta = (int*)ws;                                    // 64 B
    int* perm = (int*)(ws + 64);                             // 16 KB
    u16* Xb  = (u16*)(ws + (64 << 10));                      // 8 MB [4096][1024]
    u16* W1t = (u16*)(ws + (64 << 10) + (8  << 20));         // 16 MB [8][1024][1024]
    u16* W2t = (u16*)(ws + (64 << 10) + (24 << 20));         // 8 MB  [8][512][1024]
    u16* h1b = (u16*)(ws + (64 << 10) + (32 << 20));         // 8 MB  [4096][1024] (sorted)
    u16* W3t = (u16*)(ws + (64 << 10) + (40 << 20));         // 393 KB [8][48][512]

    // launch 1: all prework, one job per block
    prep_all<<<PA_TOT, 256, 0, stream>>>(
        xs, xp, W1, W2, W3, b3, label, meta, perm, Xb, W1t, W2t, W3t, out);

    // launch 2: L1 GEMM, 128x64 tiles -> (4096/128+8)*16 = 640 blocks
    mfma_gemm<K1n, H1n, 128, 64, true, false><<<640, 256, 0, stream>>>(
        Xb, W1t, b1, meta, perm, h1b, nullptr, out);

    // launch 3: L2 + fused L3, 64x64 tiles -> (4096/64+8)*8 = 576 blocks
    mfma_gemm<H1n, H2n, 64, 64, false, true><<<576, 256, 0, stream>>>(
        h1b, W2t, b2, meta, perm, nullptr, W3t, out);
}